// Round 7
// baseline (404.828 us; speedup 1.0000x reference)
//
#include <hip/hip_runtime.h>
#include <hip/hip_bf16.h>

// Problem constants
#define CC 768
#define MM 32768                // pixels (8*64*64)
#define NQKV 2304               // 3*CC
#define SCALE_ 0.125f           // 64^-0.5

typedef __bf16 bf16x8 __attribute__((ext_vector_type(8)));
typedef float f32x4 __attribute__((ext_vector_type(4)));
typedef unsigned short ushort8_t __attribute__((ext_vector_type(8)));

static __device__ __forceinline__ float bf2f(unsigned short u) {
  return __uint_as_float(((unsigned int)u) << 16);
}
static __device__ __forceinline__ unsigned short f2bf(float f) {
  __hip_bfloat16 t = __float2bfloat16(f);
  return __builtin_bit_cast(unsigned short, t);
}

#define FENCE() asm volatile("" ::: "memory")
#define BAR() do { FENCE(); __builtin_amdgcn_s_barrier(); FENCE(); } while (0)
#define GLDS(src, dst) __builtin_amdgcn_global_load_lds( \
    (const __attribute__((address_space(1))) void*)(src), \
    (__attribute__((address_space(3))) void*)(dst), 16, 0, 0)

// ---------------------------------------------------------------------------
// f32 -> bf16 convert (vectorized float4 -> 4x bf16)
// ---------------------------------------------------------------------------
__global__ void cvt_kernel(const float* __restrict__ in,
                           __hip_bfloat16* __restrict__ out, int n4) {
  int i = blockIdx.x * blockDim.x + threadIdx.x;
  if (i >= n4) return;
  float4 v = reinterpret_cast<const float4*>(in)[i];
  ushort4 o;
  o.x = f2bf(v.x); o.y = f2bf(v.y); o.z = f2bf(v.z); o.w = f2bf(v.w);
  reinterpret_cast<ushort4*>(out)[i] = o;
}

// ---------------------------------------------------------------------------
// 256x256 8-phase bf16 GEMM v2: D = A[M][K] * Bw[N][K]^T.
// BK=64, 2 LDS slots, 8 waves (2M x 4N), 512 threads, 128 KiB LDS.
// INTERLEAVED half-tiles so per-phase reads partition by half:
//   A-half h = rows { wr*128 + h*64 .. +63 } for wr=0,1  (local 128 rows)
//   B-half h = rows { wn*64  + h*32 .. +31 } for wn=0..3 (local 128 rows)
// Phase reads: p1 {Ah0,Bh0} p2 {Bh1} p3 {Ah1} p4 {Bh0} (s0); p5-p8 same (s1).
// Stage schedule (1 half/phase, stage-after-last-read):
//   p1 Bh0(s1,k1)[ALWAYS]  p2 Ah0(s0,k2)  p3 Bh1(s0,k2)  p4 Ah1(s0,k2)
//   p5 Bh0(s0,k2)          p6 Ah0(s1,k3)  p7 Bh1(s1,k3)  p8 Ah1(s1,k3)
// Waits: vmcnt(6) at p4-end (retires ...,p1 -> s1[k1] ready for p5-p8) and
// p8-end (retires ...,p5 -> s0[k2] ready for next p1-p4). Min cover: 3 phases.
// Last iteration: p2..p8 stages skipped, p4-end drains vmcnt(0).
// Col swizzle (rule #21, R4/R6-verified): source col-block (l&7)^(l>>3);
// read slot (ks*4+g)^(row&7). SQ_LDS_BANK_CONFLICT measured 0 in R6.
// MODE 1: bf16 TRANSPOSED outT[N][M]; MODE 2: f32 out[M][N] + bias.
// ---------------------------------------------------------------------------
template <int MODE>
__global__ __launch_bounds__(512, 2) void gemm256_kernel(
    const __hip_bfloat16* __restrict__ A,
    const __hip_bfloat16* __restrict__ Bw,
    void* __restrict__ outp,
    const float* __restrict__ bias,
    int M, int N, int K) {
  __shared__ __hip_bfloat16 lA[2][2][128 * 64];   // [slot][half][r*64+c]
  __shared__ __hip_bfloat16 lB[2][2][128 * 64];

  const int nBN = N >> 8;
  const int cpx = gridDim.x >> 3;                 // grid % 8 == 0
  const int bid = ((int)blockIdx.x & 7) * cpx + ((int)blockIdx.x >> 3);
  const int bm = bid / nBN;
  const int bn = bid % nBN;
  const int tid = threadIdx.x;
  const int lane = tid & 63;
  const int wv = tid >> 6;                        // 0..7
  const int wr = wv >> 2;                         // M-wave: rows wr*128
  const int wn = wv & 3;                          // N-wave: cols wn*64

  const size_t Abase = (size_t)(bm * 256) * K;
  const size_t Bbase = (size_t)(bn * 256) * K;

  // staging: lane covers local row (lrb + lane>>3), col-block (l&7)^(l>>3)
  const int srow8 = lane >> 3;
  const int sslot = (lane & 7) ^ srow8;

  // fragment: row&7 == lane&7 for all fragment rows
  const int fr = lane & 15;
  const int g = lane >> 4;
  const int sw = lane & 7;

  f32x4 acc[8][4] = {};

  // local row -> global row maps (interleaved halves)
  auto stageA = [&](int slot, int half, int kt) {
#pragma unroll
    for (int i = 0; i < 2; ++i) {
      const int lr = wv * 16 + i * 8 + srow8;            // local row 0..127
      const int gr = ((lr >> 6) << 7) + half * 64 + (lr & 63);
      const __hip_bfloat16* src =
          A + Abase + (size_t)gr * K + (kt << 6) + (sslot << 3);
      GLDS(src, &lA[slot][half][(wv * 16 + i * 8) << 6]);
    }
  };
  auto stageB = [&](int slot, int half, int kt) {
#pragma unroll
    for (int i = 0; i < 2; ++i) {
      const int lr = wv * 16 + i * 8 + srow8;
      const int gr = ((lr >> 5) << 6) + half * 32 + (lr & 31);
      const __hip_bfloat16* src =
          Bw + Bbase + (size_t)gr * K + (kt << 6) + (sslot << 3);
      GLDS(src, &lB[slot][half][(wv * 16 + i * 8) << 6]);
    }
  };
  auto ldA = [&](int slot, int m, int ks) -> bf16x8 {    // m in 0..7
    const int lr = wr * 64 + (m & 3) * 16 + fr;
    const int s = (ks * 4 + g) ^ sw;
    return *reinterpret_cast<const bf16x8*>(&lA[slot][m >> 2][(lr << 6) + (s << 3)]);
  };
  auto ldB = [&](int slot, int n, int ks) -> bf16x8 {    // n in 0..3
    const int lr = wn * 32 + (n & 1) * 16 + fr;
    const int s = (ks * 4 + g) ^ sw;
    return *reinterpret_cast<const bf16x8*>(&lB[slot][n >> 1][(lr << 6) + (s << 3)]);
  };

  const int nit = K >> 7;                         // 6 for K=768

  // prologue: full s0(kt=0) + {Ah0,Bh1,Ah1}(s1,kt=1); Bh0(s1,1) comes at p1
  stageA(0, 0, 0); stageA(0, 1, 0); stageB(0, 0, 0); stageB(0, 1, 0);
  stageA(1, 0, 1); stageB(1, 1, 1); stageA(1, 1, 1);
  asm volatile("s_waitcnt vmcnt(6)" ::: "memory");       // s0 complete
  BAR();

  bf16x8 a4[4][2], bA[2][2], bB[2][2];

#define MFMA_BLK(AM, BN, ACCM, ACCN)                                          \
  __builtin_amdgcn_s_setprio(1);                                              \
  _Pragma("unroll")                                                           \
  for (int m = 0; m < 4; ++m)                                                 \
    _Pragma("unroll")                                                         \
    for (int n = 0; n < 2; ++n)                                               \
      _Pragma("unroll")                                                       \
      for (int ks = 0; ks < 2; ++ks)                                          \
        acc[(ACCM) + m][(ACCN) + n] = __builtin_amdgcn_mfma_f32_16x16x32_bf16(\
            AM[m][ks], BN[n][ks], acc[(ACCM) + m][(ACCN) + n], 0, 0, 0);      \
  __builtin_amdgcn_s_setprio(0);

  for (int t = 0; t < nit; ++t) {
    const int k1 = 2 * t + 1, k2 = 2 * t + 2, k3 = 2 * t + 3;
    const bool more = (t + 1 < nit);

    // ---- p1: read Ah0+Bh0 (s0); stage Bh0(s1,k1) ALWAYS; MFMA m0-3 x n0-1
#pragma unroll
    for (int m = 0; m < 4; ++m) { a4[m][0] = ldA(0, m, 0); a4[m][1] = ldA(0, m, 1); }
#pragma unroll
    for (int n = 0; n < 2; ++n) { bA[n][0] = ldB(0, n, 0); bA[n][1] = ldB(0, n, 1); }
    stageB(1, 0, k1);
    BAR();
    MFMA_BLK(a4, bA, 0, 0)
    BAR();

    // ---- p2: read Bh1 (s0); stage Ah0(s0,k2); MFMA m0-3 x n2-3
#pragma unroll
    for (int n = 0; n < 2; ++n) { bB[n][0] = ldB(0, n + 2, 0); bB[n][1] = ldB(0, n + 2, 1); }
    if (more) stageA(0, 0, k2);
    BAR();
    MFMA_BLK(a4, bB, 0, 2)
    BAR();

    // ---- p3: read Ah1 (s0); stage Bh1(s0,k2); MFMA m4-7 x n2-3 (bB in regs)
#pragma unroll
    for (int m = 0; m < 4; ++m) { a4[m][0] = ldA(0, m + 4, 0); a4[m][1] = ldA(0, m + 4, 1); }
    if (more) stageB(0, 1, k2);
    BAR();
    MFMA_BLK(a4, bB, 4, 2)
    BAR();

    // ---- p4: read Bh0 (s0); stage Ah1(s0,k2); MFMA m4-7 x n0-1; vmcnt(6)
#pragma unroll
    for (int n = 0; n < 2; ++n) { bA[n][0] = ldB(0, n, 0); bA[n][1] = ldB(0, n, 1); }
    if (more) stageA(0, 1, k2);
    BAR();
    MFMA_BLK(a4, bA, 4, 0)
    if (more) { asm volatile("s_waitcnt vmcnt(6)" ::: "memory"); }
    else      { asm volatile("s_waitcnt vmcnt(0)" ::: "memory"); }
    BAR();

    // ---- p5: read Ah0+Bh0 (s1); stage Bh0(s0,k2); MFMA m0-3 x n0-1
#pragma unroll
    for (int m = 0; m < 4; ++m) { a4[m][0] = ldA(1, m, 0); a4[m][1] = ldA(1, m, 1); }
#pragma unroll
    for (int n = 0; n < 2; ++n) { bA[n][0] = ldB(1, n, 0); bA[n][1] = ldB(1, n, 1); }
    if (more) stageB(0, 0, k2);
    BAR();
    MFMA_BLK(a4, bA, 0, 0)
    BAR();

    // ---- p6: read Bh1 (s1); stage Ah0(s1,k3); MFMA m0-3 x n2-3
#pragma unroll
    for (int n = 0; n < 2; ++n) { bB[n][0] = ldB(1, n + 2, 0); bB[n][1] = ldB(1, n + 2, 1); }
    if (more) stageA(1, 0, k3);
    BAR();
    MFMA_BLK(a4, bB, 0, 2)
    BAR();

    // ---- p7: read Ah1 (s1); stage Bh1(s1,k3); MFMA m4-7 x n2-3
#pragma unroll
    for (int m = 0; m < 4; ++m) { a4[m][0] = ldA(1, m + 4, 0); a4[m][1] = ldA(1, m + 4, 1); }
    if (more) stageB(1, 1, k3);
    BAR();
    MFMA_BLK(a4, bB, 4, 2)
    BAR();

    // ---- p8: read Bh0 (s1); stage Ah1(s1,k3); MFMA m4-7 x n0-1; vmcnt(6)
#pragma unroll
    for (int n = 0; n < 2; ++n) { bA[n][0] = ldB(1, n, 0); bA[n][1] = ldB(1, n, 1); }
    if (more) stageA(1, 1, k3);
    BAR();
    MFMA_BLK(a4, bA, 4, 0)
    if (more) { asm volatile("s_waitcnt vmcnt(6)" ::: "memory"); }
    BAR();
  }
#undef MFMA_BLK

  // epilogue: C/D layout col = lane&15, row = (lane>>4)*4 + r   [m89]
  const int r0 = (lane >> 4) * 4;
  const int cc_ = lane & 15;
#pragma unroll
  for (int m = 0; m < 8; ++m) {
#pragma unroll
    for (int n = 0; n < 4; ++n) {
      const int grow = bm * 256 + wr * 128 + m * 16 + r0;
      const int gcol = bn * 256 + wn * 64 + n * 16 + cc_;
      if (MODE == 1) {
        __hip_bfloat16* outT = (__hip_bfloat16*)outp;
        ushort4 pk;
        pk.x = f2bf(acc[m][n][0]);
        pk.y = f2bf(acc[m][n][1]);
        pk.z = f2bf(acc[m][n][2]);
        pk.w = f2bf(acc[m][n][3]);
        *reinterpret_cast<ushort4*>(outT + (size_t)gcol * M + grow) = pk;
      } else {
        float* outF = (float*)outp;
        const float bv = bias ? bias[gcol] : 0.f;
#pragma unroll
        for (int r = 0; r < 4; ++r)
          outF[(size_t)(grow + r) * N + gcol] = acc[m][n][r] + bv;
      }
    }
  }
}

// ---------------------------------------------------------------------------
// 128x128 bf16 GEMM (R5-proven): depth-2 counted-vmcnt, 3 LDS slots,
// conflict-free swizzled staging, XCD swizzle. Used for GEMM2 (N=768).
// MODE 2: f32 out[M][N] + bias.
// ---------------------------------------------------------------------------
template <int MODE>
__global__ __launch_bounds__(256) void gemm128_kernel(
    const __hip_bfloat16* __restrict__ A,
    const __hip_bfloat16* __restrict__ Bw,
    void* __restrict__ outp,
    const float* __restrict__ bias,
    int M, int N, int K) {
  __shared__ __hip_bfloat16 lA[3][128 * 32];
  __shared__ __hip_bfloat16 lB[3][128 * 32];

  const int nBN = N >> 7;
  const int cpx = gridDim.x >> 3;
  const int bid = ((int)blockIdx.x & 7) * cpx + ((int)blockIdx.x >> 3);
  const int bm = bid / nBN;
  const int bn = bid % nBN;
  const int tid = threadIdx.x;
  const int lane = tid & 63;
  const int wv = tid >> 6;
  const int wr = wv >> 1;
  const int wc = wv & 1;

  f32x4 acc[4][4] = {};

  const int srow = wv * 16 + (lane >> 2);
  const int scol = ((lane & 3) ^ ((lane >> 3) & 3)) * 8;
  const size_t Abase = (size_t)(bm * 128) * K;
  const size_t Bbase = (size_t)(bn * 128) * K;

  const int frow = lane & 15;
  const int g = lane >> 4;
  const int fcol = (g ^ ((frow >> 1) & 3)) * 8;

  auto stage = [&](int buf, int t) {
    const int k0 = t << 5;
#pragma unroll
    for (int c = 0; c < 2; ++c) {
      const __hip_bfloat16* gA = A + Abase + (size_t)(c * 64 + srow) * K + k0 + scol;
      GLDS(gA, &lA[buf][(c * 64 + wv * 16) * 32]);
      const __hip_bfloat16* gB = Bw + Bbase + (size_t)(c * 64 + srow) * K + k0 + scol;
      GLDS(gB, &lB[buf][(c * 64 + wv * 16) * 32]);
    }
  };

  const int nt = K >> 5;
  stage(0, 0);
  if (nt > 1) stage(1, 1);

  int rd = 0;
  int st = 2;
  for (int t = 0; t < nt; ++t) {
    if (t + 1 < nt) asm volatile("s_waitcnt vmcnt(4)" ::: "memory");
    else            asm volatile("s_waitcnt vmcnt(0)" ::: "memory");
    __builtin_amdgcn_s_barrier();
    FENCE();

    bf16x8 af[4], bfr[4];
#pragma unroll
    for (int m = 0; m < 4; ++m)
      af[m] = *reinterpret_cast<const bf16x8*>(&lA[rd][(wr * 64 + m * 16 + frow) * 32 + fcol]);
#pragma unroll
    for (int n = 0; n < 4; ++n)
      bfr[n] = *reinterpret_cast<const bf16x8*>(&lB[rd][(wc * 64 + n * 16 + frow) * 32 + fcol]);

    if (t + 2 < nt) stage(st, t + 2);

#pragma unroll
    for (int m = 0; m < 4; ++m)
#pragma unroll
      for (int n = 0; n < 4; ++n)
        acc[m][n] = __builtin_amdgcn_mfma_f32_16x16x32_bf16(af[m], bfr[n], acc[m][n], 0, 0, 0);

    rd = (rd == 2) ? 0 : rd + 1;
    st = (st == 2) ? 0 : st + 1;
  }

  const int r0 = (lane >> 4) * 4;
  const int cc_ = lane & 15;
#pragma unroll
  for (int m = 0; m < 4; ++m) {
#pragma unroll
    for (int n = 0; n < 4; ++n) {
      const int grow = bm * 128 + wr * 64 + m * 16 + r0;
      const int gcol = bn * 128 + wc * 64 + n * 16 + cc_;
      if (MODE == 1) {
        __hip_bfloat16* outT = (__hip_bfloat16*)outp;
        ushort4 pk;
        pk.x = f2bf(acc[m][n][0]);
        pk.y = f2bf(acc[m][n][1]);
        pk.z = f2bf(acc[m][n][2]);
        pk.w = f2bf(acc[m][n][3]);
        *reinterpret_cast<ushort4*>(outT + (size_t)gcol * M + grow) = pk;
      } else {
        float* outF = (float*)outp;
        const float bv = bias ? bias[gcol] : 0.f;
#pragma unroll
        for (int r = 0; r < 4; ++r)
          outF[(size_t)(grow + r) * N + gcol] = acc[m][n][r] + bv;
      }
    }
  }
}

// ---------------------------------------------------------------------------
// Dilated local attention (unchanged from R5): thread = (pixel, head, half).
// ---------------------------------------------------------------------------
__global__ __launch_bounds__(256) void attn_kernel(
    const unsigned short* __restrict__ qkvT,
    const unsigned short* __restrict__ xres,
    unsigned short* __restrict__ y) {
  const int hh = blockIdx.x >> 7;              // 0..23 (uniform per block)
  const int head = hh >> 1;
  const int half = hh & 1;
  const int p = ((blockIdx.x & 127) << 8) + threadIdx.x;  // pixel
  const int h = (p >> 6) & 63;
  const int w = p & 63;
  const int grp = head >> 2;
  const int dil = grp + 1;                     // DILATIONS = (1,2,3)
  const int chq = grp * 256 + (head & 3) * 64;

  int voff[9];
  bool valid[9];
#pragma unroll
  for (int t = 0; t < 9; ++t) {
    const int di = t / 3 - 1, dj = t % 3 - 1;
    valid[t] = ((unsigned)(h + di * dil) < 64u) && ((unsigned)(w + dj * dil) < 64u);
    voff[t] = p + (di * 64 + dj) * dil + 256;  // +256 bias keeps index >= 0
  }
  const int voffq = p + 256;

  const unsigned short* qb = qkvT + (size_t)chq * MM - 256;
  const unsigned short* kb = qkvT + (size_t)(768 + chq) * MM - 256;

  float l[9] = {};
#pragma unroll 1
  for (int cb = 0; cb < 16; ++cb) {
    unsigned short qv[4];
    unsigned short kv[4][9];
#pragma unroll
    for (int i = 0; i < 4; ++i) qv[i] = qb[voffq + i * MM];
#pragma unroll
    for (int i = 0; i < 4; ++i)
#pragma unroll
      for (int t = 0; t < 9; ++t) kv[i][t] = kb[voff[t] + i * MM];
#pragma unroll
    for (int i = 0; i < 4; ++i) {
      const float qf = bf2f(qv[i]);
#pragma unroll
      for (int t = 0; t < 9; ++t)
        l[t] = fmaf(qf, bf2f(kv[i][t]), l[t]);
    }
    qb += 4 * MM;
    kb += 4 * MM;
  }

#pragma unroll
  for (int t = 0; t < 9; ++t) l[t] = valid[t] ? l[t] * SCALE_ : 0.f;
  float mx = l[0];
#pragma unroll
  for (int t = 1; t < 9; ++t) mx = fmaxf(mx, l[t]);
  float den = 0.f;
#pragma unroll
  for (int t = 0; t < 9; ++t) {
    const float e = __expf(l[t] - mx);
    den += e;                                  // invalid taps count in denom
    l[t] = valid[t] ? e : 0.f;                 // but contribute 0 to numerator
  }
  const float inv = 1.f / den;
#pragma unroll
  for (int t = 0; t < 9; ++t) l[t] *= inv;

  const int cho = chq + half * 32;
  const unsigned short* vb = qkvT + (size_t)(1536 + cho) * MM - 256;
  float vout[32];
#pragma unroll 1
  for (int cb = 0; cb < 8; ++cb) {
    unsigned short vv[4][9];
#pragma unroll
    for (int i = 0; i < 4; ++i)
#pragma unroll
      for (int t = 0; t < 9; ++t) vv[i][t] = vb[voff[t] + i * MM];
#pragma unroll
    for (int i = 0; i < 4; ++i) {
      float acc = 0.f;
#pragma unroll
      for (int t = 0; t < 9; ++t)
        acc = fmaf(l[t], bf2f(vv[i][t]), acc);
      vout[cb * 4 + i] = acc;
    }
    vb += 4 * MM;
  }

  const ushort8_t* xr = reinterpret_cast<const ushort8_t*>(xres + (size_t)p * CC + cho);
  ushort8_t* yr = reinterpret_cast<ushort8_t*>(y + (size_t)p * CC + cho);
#pragma unroll
  for (int k = 0; k < 4; ++k) {
    const ushort8_t xa = xr[k];
    ushort8_t o;
#pragma unroll
    for (int j = 0; j < 8; ++j)
      o[j] = f2bf(vout[8 * k + j] + bf2f(xa[j]));
    yr[k] = o;
  }
}

// ---------------------------------------------------------------------------
// launch
// ---------------------------------------------------------------------------
extern "C" void kernel_launch(void* const* d_in, const int* in_sizes, int n_in,
                              void* d_out, int out_size, void* d_ws, size_t ws_size,
                              hipStream_t stream) {
  const float* x = (const float*)d_in[0];
  const float* qkv_w = (const float*)d_in[1];
  const float* proj_w = (const float*)d_in[2];
  const float* proj_b = (const float*)d_in[3];
  float* out = (float*)d_out;

  char* ws = (char*)d_ws;
  // ws layout (bytes), total 206,045,184:
  //   [0, 50331648)            xb [M][768] bf16  -> reused as y [M][768] bf16
  //   [50331648, 201326592)    qkvT [2304][M] bf16
  //   [201326592, 204865536)   wqkvb [2304][768] bf16 (absorbs OOB tap reads)
  //   [204865536, 206045184)   wprojb [768][768] bf16
  __hip_bfloat16* xb = (__hip_bfloat16*)(ws);
  __hip_bfloat16* qkvT = (__hip_bfloat16*)(ws + 50331648);
  __hip_bfloat16* wqkvb = (__hip_bfloat16*)(ws + 201326592);
  __hip_bfloat16* wprojb = (__hip_bfloat16*)(ws + 204865536);
  __hip_bfloat16* ybuf = xb;                   // y overwrites xb (per-thread
                                               // read-then-write, exclusive)

  cvt_kernel<<<(MM * CC / 4 + 255) / 256, 256, 0, stream>>>(x, xb, MM * CC / 4);
  cvt_kernel<<<(NQKV * CC / 4 + 255) / 256, 256, 0, stream>>>(qkv_w, wqkvb, NQKV * CC / 4);
  cvt_kernel<<<(CC * CC / 4 + 255) / 256, 256, 0, stream>>>(proj_w, wprojb, CC * CC / 4);

  // qkv GEMM -> channel-major qkvT [2304][M]   (grid 1152 % 8 == 0)
  gemm256_kernel<1><<<(MM / 256) * (NQKV / 256), 512, 0, stream>>>(
      xb, wqkvb, (void*)qkvT, nullptr, MM, NQKV, CC);

  // attention + residual -> y [M][768] bf16 (24 head-halves x 128 pixel-blocks)
  attn_kernel<<<24 * 128, 256, 0, stream>>>(
      (const unsigned short*)qkvT, (const unsigned short*)xb,
      (unsigned short*)ybuf);

  // proj GEMM -> f32 out [M][768] + bias      (grid 1536 % 8 == 0)
  gemm128_kernel<2><<<(MM / 128) * (CC / 128), 256, 0, stream>>>(
      ybuf, wprojb, (void*)out, proj_b, MM, CC, CC);
}

// Round 8
// 381.773 us; speedup vs baseline: 1.0604x; 1.0604x over previous
//
#include <hip/hip_runtime.h>
#include <hip/hip_bf16.h>

// Problem constants
#define CC 768
#define MM 32768                // pixels (8*64*64)
#define NQKV 2304               // 3*CC
#define SCALE_ 0.125f           // 64^-0.5

typedef __bf16 bf16x8 __attribute__((ext_vector_type(8)));
typedef float f32x4 __attribute__((ext_vector_type(4)));
typedef unsigned short ushort8_t __attribute__((ext_vector_type(8)));

static __device__ __forceinline__ float bf2f(unsigned short u) {
  return __uint_as_float(((unsigned int)u) << 16);
}
static __device__ __forceinline__ unsigned short f2bf(float f) {
  __hip_bfloat16 t = __float2bfloat16(f);
  return __builtin_bit_cast(unsigned short, t);
}

#define FENCE() asm volatile("" ::: "memory")
#define GLDS(src, dst) __builtin_amdgcn_global_load_lds( \
    (const __attribute__((address_space(1))) void*)(src), \
    (__attribute__((address_space(3))) void*)(dst), 16, 0, 0)

// ---------------------------------------------------------------------------
// fused f32 -> bf16 convert over the 3 input regions (x, qkv_w, proj_w).
// One launch instead of three; region pick is wave-uniform except at the
// 2 boundaries. Quad counts: x 6291456, qkv_w 442368, proj_w 147456.
// ---------------------------------------------------------------------------
#define N4_X     (MM * CC / 4)
#define N4_WQKV  (NQKV * CC / 4)
#define N4_WPROJ (CC * CC / 4)

__global__ void cvt3_kernel(const float* __restrict__ x,
                            const float* __restrict__ qw,
                            const float* __restrict__ pw,
                            __hip_bfloat16* __restrict__ xb,
                            __hip_bfloat16* __restrict__ wqkvb,
                            __hip_bfloat16* __restrict__ wprojb) {
  int i = blockIdx.x * blockDim.x + threadIdx.x;
  const float* in;
  __hip_bfloat16* out;
  if (i < N4_X) {
    in = x; out = xb;
  } else if (i < N4_X + N4_WQKV) {
    i -= N4_X; in = qw; out = wqkvb;
  } else {
    i -= N4_X + N4_WQKV; in = pw; out = wprojb;
  }
  float4 v = reinterpret_cast<const float4*>(in)[i];
  ushort4 o;
  o.x = f2bf(v.x); o.y = f2bf(v.y); o.z = f2bf(v.z); o.w = f2bf(v.w);
  reinterpret_cast<ushort4*>(out)[i] = o;
}

// ---------------------------------------------------------------------------
// bf16 GEMM (R5-proven): D = A[M][K] * Bw[N][K]^T. 128x128 tile, BK=32,
// 4 waves (2x2). Depth-2 counted-vmcnt pipeline (3 LDS buffer sets):
//   per iter: s_waitcnt vmcnt(4) -> s_barrier -> ds_read buf[t%3] ->
//             stage t+2 -> 16x MFMA.   vmcnt never drains to 0 mid-loop.
// Conflict-free LDS (rule #21): linear LDS dest, col-block-permuted GLOBAL
// source ((l&3)^((l>>3)&3)), matching XOR on the read side (measured 0
// SQ_LDS_BANK_CONFLICT). XCD-aware block swizzle (grid % 8 == 0).
// MODE 1: bf16 TRANSPOSED outT[N][M]; MODE 2: f32 out[M][N] + bias.
// ---------------------------------------------------------------------------
template <int MODE>
__global__ __launch_bounds__(256) void gemm_bf16_kernel(
    const __hip_bfloat16* __restrict__ A,
    const __hip_bfloat16* __restrict__ Bw,
    void* __restrict__ outp,
    const float* __restrict__ bias,
    int M, int N, int K) {
  __shared__ __hip_bfloat16 lA[3][128 * 32];
  __shared__ __hip_bfloat16 lB[3][128 * 32];

  const int nBN = N >> 7;
  const int cpx = gridDim.x >> 3;
  const int bid = ((int)blockIdx.x & 7) * cpx + ((int)blockIdx.x >> 3);
  const int bm = bid / nBN;
  const int bn = bid % nBN;
  const int tid = threadIdx.x;
  const int lane = tid & 63;
  const int wv = tid >> 6;
  const int wr = wv >> 1;
  const int wc = wv & 1;

  f32x4 acc[4][4] = {};

  const int srow = wv * 16 + (lane >> 2);
  const int scol = ((lane & 3) ^ ((lane >> 3) & 3)) * 8;
  const size_t Abase = (size_t)(bm * 128) * K;
  const size_t Bbase = (size_t)(bn * 128) * K;

  const int frow = lane & 15;
  const int g = lane >> 4;
  const int fcol = (g ^ ((frow >> 1) & 3)) * 8;

  auto stage = [&](int buf, int t) {
    const int k0 = t << 5;
#pragma unroll
    for (int c = 0; c < 2; ++c) {
      const __hip_bfloat16* gA = A + Abase + (size_t)(c * 64 + srow) * K + k0 + scol;
      GLDS(gA, &lA[buf][(c * 64 + wv * 16) * 32]);
      const __hip_bfloat16* gB = Bw + Bbase + (size_t)(c * 64 + srow) * K + k0 + scol;
      GLDS(gB, &lB[buf][(c * 64 + wv * 16) * 32]);
    }
  };

  const int nt = K >> 5;                     // 24 for K=768
  stage(0, 0);
  if (nt > 1) stage(1, 1);

  int rd = 0;
  int st = 2;
  for (int t = 0; t < nt; ++t) {
    if (t + 1 < nt) asm volatile("s_waitcnt vmcnt(4)" ::: "memory");
    else            asm volatile("s_waitcnt vmcnt(0)" ::: "memory");
    __builtin_amdgcn_s_barrier();
    FENCE();

    bf16x8 af[4], bfr[4];
#pragma unroll
    for (int m = 0; m < 4; ++m)
      af[m] = *reinterpret_cast<const bf16x8*>(&lA[rd][(wr * 64 + m * 16 + frow) * 32 + fcol]);
#pragma unroll
    for (int n = 0; n < 4; ++n)
      bfr[n] = *reinterpret_cast<const bf16x8*>(&lB[rd][(wc * 64 + n * 16 + frow) * 32 + fcol]);

    if (t + 2 < nt) stage(st, t + 2);

#pragma unroll
    for (int m = 0; m < 4; ++m)
#pragma unroll
      for (int n = 0; n < 4; ++n)
        acc[m][n] = __builtin_amdgcn_mfma_f32_16x16x32_bf16(af[m], bfr[n], acc[m][n], 0, 0, 0);

    rd = (rd == 2) ? 0 : rd + 1;
    st = (st == 2) ? 0 : st + 1;
  }

  // C/D layout: col = lane&15, row = (lane>>4)*4 + r   [m89]
  const int r0 = (lane >> 4) * 4;
  const int cc_ = lane & 15;
#pragma unroll
  for (int m = 0; m < 4; ++m) {
#pragma unroll
    for (int n = 0; n < 4; ++n) {
      const int grow = bm * 128 + wr * 64 + m * 16 + r0;
      const int gcol = bn * 128 + wc * 64 + n * 16 + cc_;
      if (MODE == 1) {
        __hip_bfloat16* outT = (__hip_bfloat16*)outp;
        ushort4 pk;
        pk.x = f2bf(acc[m][n][0]);
        pk.y = f2bf(acc[m][n][1]);
        pk.z = f2bf(acc[m][n][2]);
        pk.w = f2bf(acc[m][n][3]);
        *reinterpret_cast<ushort4*>(outT + (size_t)gcol * M + grow) = pk;
      } else {
        float* outF = (float*)outp;
        const float bv = bias ? bias[gcol] : 0.f;
#pragma unroll
        for (int r = 0; r < 4; ++r)
          outF[(size_t)(grow + r) * N + gcol] = acc[m][n][r] + bv;
      }
    }
  }
}

// ---------------------------------------------------------------------------
// Dilated local attention (R5-proven): thread = (pixel, head, half).
//  - channel-split x2: vout[32], 12288 waves
//  - explicit load batching (4 channels/batch): ~40 independent ushort loads
//    in flight per wave
//  - residual read from bf16 xb; y aliases xb (exclusive per-thread range)
// OOB taps: logit 0 in denominator, 0 in numerator (zero-pad reference).
// OOB reads land inside workspace (adjacent planes / weight region).
// ---------------------------------------------------------------------------
__global__ __launch_bounds__(256) void attn_kernel(
    const unsigned short* __restrict__ qkvT,
    const unsigned short* __restrict__ xres,
    unsigned short* __restrict__ y) {
  const int hh = blockIdx.x >> 7;              // 0..23 (uniform per block)
  const int head = hh >> 1;
  const int half = hh & 1;
  const int p = ((blockIdx.x & 127) << 8) + threadIdx.x;  // pixel
  const int h = (p >> 6) & 63;
  const int w = p & 63;
  const int grp = head >> 2;
  const int dil = grp + 1;                     // DILATIONS = (1,2,3)
  const int chq = grp * 256 + (head & 3) * 64;

  int voff[9];
  bool valid[9];
#pragma unroll
  for (int t = 0; t < 9; ++t) {
    const int di = t / 3 - 1, dj = t % 3 - 1;
    valid[t] = ((unsigned)(h + di * dil) < 64u) && ((unsigned)(w + dj * dil) < 64u);
    voff[t] = p + (di * 64 + dj) * dil + 256;  // +256 bias keeps index >= 0
  }
  const int voffq = p + 256;

  const unsigned short* qb = qkvT + (size_t)chq * MM - 256;
  const unsigned short* kb = qkvT + (size_t)(768 + chq) * MM - 256;

  float l[9] = {};
#pragma unroll 1
  for (int cb = 0; cb < 16; ++cb) {
    unsigned short qv[4];
    unsigned short kv[4][9];
#pragma unroll
    for (int i = 0; i < 4; ++i) qv[i] = qb[voffq + i * MM];
#pragma unroll
    for (int i = 0; i < 4; ++i)
#pragma unroll
      for (int t = 0; t < 9; ++t) kv[i][t] = kb[voff[t] + i * MM];
#pragma unroll
    for (int i = 0; i < 4; ++i) {
      const float qf = bf2f(qv[i]);
#pragma unroll
      for (int t = 0; t < 9; ++t)
        l[t] = fmaf(qf, bf2f(kv[i][t]), l[t]);
    }
    qb += 4 * MM;
    kb += 4 * MM;
  }

#pragma unroll
  for (int t = 0; t < 9; ++t) l[t] = valid[t] ? l[t] * SCALE_ : 0.f;
  float mx = l[0];
#pragma unroll
  for (int t = 1; t < 9; ++t) mx = fmaxf(mx, l[t]);
  float den = 0.f;
#pragma unroll
  for (int t = 0; t < 9; ++t) {
    const float e = __expf(l[t] - mx);
    den += e;                                  // invalid taps count in denom
    l[t] = valid[t] ? e : 0.f;                 // but contribute 0 to numerator
  }
  const float inv = 1.f / den;
#pragma unroll
  for (int t = 0; t < 9; ++t) l[t] *= inv;

  const int cho = chq + half * 32;
  const unsigned short* vb = qkvT + (size_t)(1536 + cho) * MM - 256;
  float vout[32];
#pragma unroll 1
  for (int cb = 0; cb < 8; ++cb) {
    unsigned short vv[4][9];
#pragma unroll
    for (int i = 0; i < 4; ++i)
#pragma unroll
      for (int t = 0; t < 9; ++t) vv[i][t] = vb[voff[t] + i * MM];
#pragma unroll
    for (int i = 0; i < 4; ++i) {
      float acc = 0.f;
#pragma unroll
      for (int t = 0; t < 9; ++t)
        acc = fmaf(l[t], bf2f(vv[i][t]), acc);
      vout[cb * 4 + i] = acc;
    }
    vb += 4 * MM;
  }

  const ushort8_t* xr = reinterpret_cast<const ushort8_t*>(xres + (size_t)p * CC + cho);
  ushort8_t* yr = reinterpret_cast<ushort8_t*>(y + (size_t)p * CC + cho);
#pragma unroll
  for (int k = 0; k < 4; ++k) {
    const ushort8_t xa = xr[k];
    ushort8_t o;
#pragma unroll
    for (int j = 0; j < 8; ++j)
      o[j] = f2bf(vout[8 * k + j] + bf2f(xa[j]));
    yr[k] = o;
  }
}

// ---------------------------------------------------------------------------
// launch
// ---------------------------------------------------------------------------
extern "C" void kernel_launch(void* const* d_in, const int* in_sizes, int n_in,
                              void* d_out, int out_size, void* d_ws, size_t ws_size,
                              hipStream_t stream) {
  const float* x = (const float*)d_in[0];
  const float* qkv_w = (const float*)d_in[1];
  const float* proj_w = (const float*)d_in[2];
  const float* proj_b = (const float*)d_in[3];
  float* out = (float*)d_out;

  char* ws = (char*)d_ws;
  // ws layout (bytes), total 206,045,184:
  //   [0, 50331648)            xb [M][768] bf16  -> reused as y [M][768] bf16
  //   [50331648, 201326592)    qkvT [2304][M] bf16
  //   [201326592, 204865536)   wqkvb [2304][768] bf16 (absorbs OOB tap reads)
  //   [204865536, 206045184)   wprojb [768][768] bf16
  __hip_bfloat16* xb = (__hip_bfloat16*)(ws);
  __hip_bfloat16* qkvT = (__hip_bfloat16*)(ws + 50331648);
  __hip_bfloat16* wqkvb = (__hip_bfloat16*)(ws + 201326592);
  __hip_bfloat16* wprojb = (__hip_bfloat16*)(ws + 204865536);
  __hip_bfloat16* ybuf = xb;                   // y overwrites xb (per-thread
                                               // read-then-write, exclusive)

  // fused f32->bf16 converts: (6291456 + 442368 + 147456) / 256 = 26880 blocks
  cvt3_kernel<<<(N4_X + N4_WQKV + N4_WPROJ) / 256, 256, 0, stream>>>(
      x, qkv_w, proj_w, xb, wqkvb, wprojb);

  // qkv GEMM -> channel-major qkvT [2304][M]   (grid 4608 % 8 == 0)
  gemm_bf16_kernel<1><<<(MM / 128) * (NQKV / 128), 256, 0, stream>>>(
      xb, wqkvb, (void*)qkvT, nullptr, MM, NQKV, CC);

  // attention + residual -> y [M][768] bf16 (24 head-halves x 128 pixel-blocks)
  attn_kernel<<<24 * 128, 256, 0, stream>>>(
      (const unsigned short*)qkvT, (const unsigned short*)xb,
      (unsigned short*)ybuf);

  // proj GEMM -> f32 out [M][768] + bias      (grid 1536 % 8 == 0)
  gemm_bf16_kernel<2><<<(MM / 128) * (CC / 128), 256, 0, stream>>>(
      ybuf, wprojb, (void*)out, proj_b, MM, CC, CC);
}

// Round 9
// 350.706 us; speedup vs baseline: 1.1543x; 1.0886x over previous
//
#include <hip/hip_runtime.h>
#include <hip/hip_bf16.h>

// Problem constants
#define CC 768
#define MM 32768                // pixels (8*64*64)
#define NQKV 2304               // 3*CC
#define SCALE_ 0.125f           // 64^-0.5

typedef __bf16 bf16x8 __attribute__((ext_vector_type(8)));
typedef float f32x4 __attribute__((ext_vector_type(4)));
typedef unsigned short ushort8_t __attribute__((ext_vector_type(8)));

static __device__ __forceinline__ float bf2f(unsigned short u) {
  return __uint_as_float(((unsigned int)u) << 16);
}
static __device__ __forceinline__ unsigned short f2bf(float f) {
  __hip_bfloat16 t = __float2bfloat16(f);
  return __builtin_bit_cast(unsigned short, t);
}

#define FENCE() asm volatile("" ::: "memory")
#define GLDS(src, dst) __builtin_amdgcn_global_load_lds( \
    (const __attribute__((address_space(1))) void*)(src), \
    (__attribute__((address_space(3))) void*)(dst), 16, 0, 0)

// ---------------------------------------------------------------------------
// fused f32 -> bf16 convert over the 3 input regions (x, qkv_w, proj_w).
// ---------------------------------------------------------------------------
#define N4_X     (MM * CC / 4)
#define N4_WQKV  (NQKV * CC / 4)
#define N4_WPROJ (CC * CC / 4)

__global__ void cvt3_kernel(const float* __restrict__ x,
                            const float* __restrict__ qw,
                            const float* __restrict__ pw,
                            __hip_bfloat16* __restrict__ xb,
                            __hip_bfloat16* __restrict__ wqkvb,
                            __hip_bfloat16* __restrict__ wprojb) {
  int i = blockIdx.x * blockDim.x + threadIdx.x;
  const float* in;
  __hip_bfloat16* out;
  if (i < N4_X) {
    in = x; out = xb;
  } else if (i < N4_X + N4_WQKV) {
    i -= N4_X; in = qw; out = wqkvb;
  } else {
    i -= N4_X + N4_WQKV; in = pw; out = wprojb;
  }
  float4 v = reinterpret_cast<const float4*>(in)[i];
  ushort4 o;
  o.x = f2bf(v.x); o.y = f2bf(v.y); o.z = f2bf(v.z); o.w = f2bf(v.w);
  reinterpret_cast<ushort4*>(out)[i] = o;
}

// ---------------------------------------------------------------------------
// bf16 GEMM (R5-proven K-loop): D = A[M][K] * Bw[N][K]^T. 128x128 tile,
// BK=32, 4 waves (2x2). Depth-2 counted-vmcnt pipeline (3 LDS buffer sets);
// conflict-free swizzled staging (rule #21); XCD-aware block swizzle.
// MODE 1: bf16 TRANSPOSED outT[N][M] via LDS-transposed COALESCED epilogue:
//   wave writes its 64x64 C-subtile col-major (stride 72) into the dead
//   staging LDS, reads back ushort8 chunks, stores 128B-contiguous runs
//   per outT column (8 lanes x 16B). 8B-scatter -> full coalescing.
// MODE 2: f32 out[M][N] + bias (row-major, unchanged).
// ---------------------------------------------------------------------------
template <int MODE>
__global__ __launch_bounds__(256) void gemm_bf16_kernel(
    const __hip_bfloat16* __restrict__ A,
    const __hip_bfloat16* __restrict__ Bw,
    void* __restrict__ outp,
    const float* __restrict__ bias,
    int M, int N, int K) {
  // single block so [A 3-buf][B 3-buf] layout is guaranteed contiguous;
  // epilogue reuses the whole 48 KiB as transpose scratch.
  __shared__ __hip_bfloat16 lds[2][3][128 * 32];

  const int nBN = N >> 7;
  const int cpx = gridDim.x >> 3;
  const int bid = ((int)blockIdx.x & 7) * cpx + ((int)blockIdx.x >> 3);
  const int bm = bid / nBN;
  const int bn = bid % nBN;
  const int tid = threadIdx.x;
  const int lane = tid & 63;
  const int wv = tid >> 6;
  const int wr = wv >> 1;
  const int wc = wv & 1;

  f32x4 acc[4][4] = {};

  const int srow = wv * 16 + (lane >> 2);
  const int scol = ((lane & 3) ^ ((lane >> 3) & 3)) * 8;
  const size_t Abase = (size_t)(bm * 128) * K;
  const size_t Bbase = (size_t)(bn * 128) * K;

  const int frow = lane & 15;
  const int g = lane >> 4;
  const int fcol = (g ^ ((frow >> 1) & 3)) * 8;

  auto stage = [&](int buf, int t) {
    const int k0 = t << 5;
#pragma unroll
    for (int c = 0; c < 2; ++c) {
      const __hip_bfloat16* gA = A + Abase + (size_t)(c * 64 + srow) * K + k0 + scol;
      GLDS(gA, &lds[0][buf][(c * 64 + wv * 16) * 32]);
      const __hip_bfloat16* gB = Bw + Bbase + (size_t)(c * 64 + srow) * K + k0 + scol;
      GLDS(gB, &lds[1][buf][(c * 64 + wv * 16) * 32]);
    }
  };

  const int nt = K >> 5;                     // 24 for K=768
  stage(0, 0);
  if (nt > 1) stage(1, 1);

  int rd = 0;
  int st = 2;
  for (int t = 0; t < nt; ++t) {
    if (t + 1 < nt) asm volatile("s_waitcnt vmcnt(4)" ::: "memory");
    else            asm volatile("s_waitcnt vmcnt(0)" ::: "memory");
    __builtin_amdgcn_s_barrier();
    FENCE();

    bf16x8 af[4], bfr[4];
#pragma unroll
    for (int m = 0; m < 4; ++m)
      af[m] = *reinterpret_cast<const bf16x8*>(&lds[0][rd][(wr * 64 + m * 16 + frow) * 32 + fcol]);
#pragma unroll
    for (int n = 0; n < 4; ++n)
      bfr[n] = *reinterpret_cast<const bf16x8*>(&lds[1][rd][(wc * 64 + n * 16 + frow) * 32 + fcol]);

    if (t + 2 < nt) stage(st, t + 2);

#pragma unroll
    for (int m = 0; m < 4; ++m)
#pragma unroll
      for (int n = 0; n < 4; ++n)
        acc[m][n] = __builtin_amdgcn_mfma_f32_16x16x32_bf16(af[m], bfr[n], acc[m][n], 0, 0, 0);

    rd = (rd == 2) ? 0 : rd + 1;
    st = (st == 2) ? 0 : st + 1;
  }

  // C/D layout: col = lane&15, row = (lane>>4)*4 + r   [m89]
  const int r0 = (lane >> 4) * 4;
  const int cc_ = lane & 15;

  if (MODE == 1) {
    // ---- LDS-transposed coalesced epilogue ----
    // barrier: all waves' final ds_reads are consumed (pre-MFMA lgkm waits)
    // before anyone repurposes the staging LDS.
    __syncthreads();
    // per-wave private region: 64 cols x stride 72 ushorts = 9216 B
    unsigned short* tb =
        reinterpret_cast<unsigned short*>(&lds[0][0][0]) + wv * 4608;
#pragma unroll
    for (int m = 0; m < 4; ++m) {
#pragma unroll
      for (int n = 0; n < 4; ++n) {
        ushort4 pk;
        pk.x = f2bf(acc[m][n][0]);
        pk.y = f2bf(acc[m][n][1]);
        pk.z = f2bf(acc[m][n][2]);
        pk.w = f2bf(acc[m][n][3]);
        // col-major: [col][row], col = n*16+cc_, rows m*16+r0..+3 (8B write)
        *reinterpret_cast<ushort4*>(tb + (n * 16 + cc_) * 72 + m * 16 + r0) = pk;
      }
    }
    // read back: lane (j = lane>>3, k = lane&7); 8 rounds x 8 cols;
    // per col: 8 lanes x 16B = 128B contiguous along M in outT.
    const int j = lane >> 3;
    const int k = lane & 7;
    __hip_bfloat16* outT = (__hip_bfloat16*)outp;
    const int gcol0 = bn * 128 + wc * 64;
    const int grow0 = bm * 128 + wr * 64 + k * 8;
#pragma unroll
    for (int rr = 0; rr < 8; ++rr) {
      const ushort8_t v =
          *reinterpret_cast<const ushort8_t*>(tb + (rr * 8 + j) * 72 + k * 8);
      *reinterpret_cast<ushort8_t*>(
          outT + (size_t)(gcol0 + rr * 8 + j) * M + grow0) = v;
    }
  } else {
#pragma unroll
    for (int m = 0; m < 4; ++m) {
#pragma unroll
      for (int n = 0; n < 4; ++n) {
        const int grow = bm * 128 + wr * 64 + m * 16 + r0;
        const int gcol = bn * 128 + wc * 64 + n * 16 + cc_;
        float* outF = (float*)outp;
        const float bv = bias ? bias[gcol] : 0.f;
#pragma unroll
        for (int r = 0; r < 4; ++r)
          outF[(size_t)(grow + r) * N + gcol] = acc[m][n][r] + bv;
      }
    }
  }
}

// ---------------------------------------------------------------------------
// Dilated local attention (R5-proven): thread = (pixel, head, half).
// ---------------------------------------------------------------------------
__global__ __launch_bounds__(256) void attn_kernel(
    const unsigned short* __restrict__ qkvT,
    const unsigned short* __restrict__ xres,
    unsigned short* __restrict__ y) {
  const int hh = blockIdx.x >> 7;              // 0..23 (uniform per block)
  const int head = hh >> 1;
  const int half = hh & 1;
  const int p = ((blockIdx.x & 127) << 8) + threadIdx.x;  // pixel
  const int h = (p >> 6) & 63;
  const int w = p & 63;
  const int grp = head >> 2;
  const int dil = grp + 1;                     // DILATIONS = (1,2,3)
  const int chq = grp * 256 + (head & 3) * 64;

  int voff[9];
  bool valid[9];
#pragma unroll
  for (int t = 0; t < 9; ++t) {
    const int di = t / 3 - 1, dj = t % 3 - 1;
    valid[t] = ((unsigned)(h + di * dil) < 64u) && ((unsigned)(w + dj * dil) < 64u);
    voff[t] = p + (di * 64 + dj) * dil + 256;  // +256 bias keeps index >= 0
  }
  const int voffq = p + 256;

  const unsigned short* qb = qkvT + (size_t)chq * MM - 256;
  const unsigned short* kb = qkvT + (size_t)(768 + chq) * MM - 256;

  float l[9] = {};
#pragma unroll 1
  for (int cb = 0; cb < 16; ++cb) {
    unsigned short qv[4];
    unsigned short kv[4][9];
#pragma unroll
    for (int i = 0; i < 4; ++i) qv[i] = qb[voffq + i * MM];
#pragma unroll
    for (int i = 0; i < 4; ++i)
#pragma unroll
      for (int t = 0; t < 9; ++t) kv[i][t] = kb[voff[t] + i * MM];
#pragma unroll
    for (int i = 0; i < 4; ++i) {
      const float qf = bf2f(qv[i]);
#pragma unroll
      for (int t = 0; t < 9; ++t)
        l[t] = fmaf(qf, bf2f(kv[i][t]), l[t]);
    }
    qb += 4 * MM;
    kb += 4 * MM;
  }

#pragma unroll
  for (int t = 0; t < 9; ++t) l[t] = valid[t] ? l[t] * SCALE_ : 0.f;
  float mx = l[0];
#pragma unroll
  for (int t = 1; t < 9; ++t) mx = fmaxf(mx, l[t]);
  float den = 0.f;
#pragma unroll
  for (int t = 0; t < 9; ++t) {
    const float e = __expf(l[t] - mx);
    den += e;                                  // invalid taps count in denom
    l[t] = valid[t] ? e : 0.f;                 // but contribute 0 to numerator
  }
  const float inv = 1.f / den;
#pragma unroll
  for (int t = 0; t < 9; ++t) l[t] *= inv;

  const int cho = chq + half * 32;
  const unsigned short* vb = qkvT + (size_t)(1536 + cho) * MM - 256;
  float vout[32];
#pragma unroll 1
  for (int cb = 0; cb < 8; ++cb) {
    unsigned short vv[4][9];
#pragma unroll
    for (int i = 0; i < 4; ++i)
#pragma unroll
      for (int t = 0; t < 9; ++t) vv[i][t] = vb[voff[t] + i * MM];
#pragma unroll
    for (int i = 0; i < 4; ++i) {
      float acc = 0.f;
#pragma unroll
      for (int t = 0; t < 9; ++t)
        acc = fmaf(l[t], bf2f(vv[i][t]), acc);
      vout[cb * 4 + i] = acc;
    }
    vb += 4 * MM;
  }

  const ushort8_t* xr = reinterpret_cast<const ushort8_t*>(xres + (size_t)p * CC + cho);
  ushort8_t* yr = reinterpret_cast<ushort8_t*>(y + (size_t)p * CC + cho);
#pragma unroll
  for (int k = 0; k < 4; ++k) {
    const ushort8_t xa = xr[k];
    ushort8_t o;
#pragma unroll
    for (int j = 0; j < 8; ++j)
      o[j] = f2bf(vout[8 * k + j] + bf2f(xa[j]));
    yr[k] = o;
  }
}

// ---------------------------------------------------------------------------
// launch
// ---------------------------------------------------------------------------
extern "C" void kernel_launch(void* const* d_in, const int* in_sizes, int n_in,
                              void* d_out, int out_size, void* d_ws, size_t ws_size,
                              hipStream_t stream) {
  const float* x = (const float*)d_in[0];
  const float* qkv_w = (const float*)d_in[1];
  const float* proj_w = (const float*)d_in[2];
  const float* proj_b = (const float*)d_in[3];
  float* out = (float*)d_out;

  char* ws = (char*)d_ws;
  // ws layout (bytes), total 206,045,184:
  //   [0, 50331648)            xb [M][768] bf16  -> reused as y [M][768] bf16
  //   [50331648, 201326592)    qkvT [2304][M] bf16
  //   [201326592, 204865536)   wqkvb [2304][768] bf16 (absorbs OOB tap reads)
  //   [204865536, 206045184)   wprojb [768][768] bf16
  __hip_bfloat16* xb = (__hip_bfloat16*)(ws);
  __hip_bfloat16* qkvT = (__hip_bfloat16*)(ws + 50331648);
  __hip_bfloat16* wqkvb = (__hip_bfloat16*)(ws + 201326592);
  __hip_bfloat16* wprojb = (__hip_bfloat16*)(ws + 204865536);
  __hip_bfloat16* ybuf = xb;                   // y overwrites xb (per-thread
                                               // read-then-write, exclusive)

  // fused f32->bf16 converts: (6291456 + 442368 + 147456) / 256 = 26880 blocks
  cvt3_kernel<<<(N4_X + N4_WQKV + N4_WPROJ) / 256, 256, 0, stream>>>(
      x, qkv_w, proj_w, xb, wqkvb, wprojb);

  // qkv GEMM -> channel-major qkvT [2304][M]   (grid 4608 % 8 == 0)
  gemm_bf16_kernel<1><<<(MM / 128) * (NQKV / 128), 256, 0, stream>>>(
      xb, wqkvb, (void*)qkvT, nullptr, MM, NQKV, CC);

  // attention + residual -> y [M][768] bf16 (24 head-halves x 128 pixel-blocks)
  attn_kernel<<<24 * 128, 256, 0, stream>>>(
      (const unsigned short*)qkvT, (const unsigned short*)xb,
      (unsigned short*)ybuf);

  // proj GEMM -> f32 out [M][768] + bias      (grid 1536 % 8 == 0)
  gemm_bf16_kernel<2><<<(MM / 128) * (CC / 128), 256, 0, stream>>>(
      ybuf, wprojb, (void*)out, proj_b, MM, CC, CC);
}